// Round 15
// baseline (215.378 us; speedup 1.0000x reference)
//
#include <hip/hip_runtime.h>

// ---------------------------------------------------------------------------
// EncoderBlock: pre-LN transformer block, B=2 S=2048 D=1024 H=16 dk=64 F=4096
// R15: attention = R8 core (KVBLK=64, reg-staged, best measured 60.6us) +
//     T15 double-pipeline: softmax+PV of tile t-1 overlaps QK MFMA of tile t
//     (2-slot LDS, same 2-barrier/iter structure). cvt_all+LN1 merged into
//     one launch. GEMMs unchanged (gemm256 4-slot; gemm128sq 4-slot; FFN2
//     K-split-2 + combine).
// Workspace layout (80 MB used):
//   [0,6M)    wqkv bf16 (dead after QKV) -> p0 bf16 for FFN2
//   [6M,8M)   wo bf16
//   [8M,16M)  w1 bf16
//   [16M,24M) w2 bf16
//   [24M,32M) xn bf16 (LN out; dead after FFN1) -> p1 bf16 for FFN2
//   [32M,40M) q bf16 [B,H,S,64] (scaled by 0.125*log2e)  } reused as h for FFN1
//   [40M,48M) k bf16 [B,H,S,64]                          }
//   [48M,56M) vT bf16 [B,H,64,S]                         }
//   [56M,64M) ctx bf16 flat [B*S,1024]                   }
//   [64M,80M) x1 fp32 (residual after attention)
// ---------------------------------------------------------------------------

typedef __bf16 bf16_t;
typedef __attribute__((ext_vector_type(8))) __bf16 bf16x8;
typedef __attribute__((ext_vector_type(4))) __bf16 bf16x4;
typedef __attribute__((ext_vector_type(2))) __bf16 bf16x2;
typedef __attribute__((ext_vector_type(4))) float f32x4;
typedef __attribute__((ext_vector_type(16))) float f32x16;
typedef __attribute__((ext_vector_type(2))) unsigned uint32x2;
typedef __attribute__((ext_vector_type(4))) unsigned uint32x4;

#define MB (1024ull * 1024ull)
#define QSCALE 0.18033688011112043f /* 0.125 * log2(e) */

__device__ __forceinline__ void gload_lds16(const bf16_t* g, bf16_t* l) {
    __builtin_amdgcn_global_load_lds(
        (const __attribute__((address_space(1))) void*)g,
        (__attribute__((address_space(3))) void*)l, 16, 0, 0);
}

// Bank-slot XOR for BK=32 (64B) LDS rows: slot ^= (row>>1)&3 (2-way max).
__device__ __forceinline__ int bswz(int row) { return ((row >> 1) & 3) << 3; }

// XOR swizzle for 64-col bf16 LDS tiles (128B rows, 8 chunks).
__device__ __forceinline__ int swz(int row, int col) {
    return row * 64 + ((((col >> 3) ^ row) & 7) << 3) + (col & 7);
}

__device__ __forceinline__ unsigned cvtpk(float a, float b) {
    bf16x2 v = {(__bf16)a, (__bf16)b};
    return __builtin_bit_cast(unsigned, v);
}

// ---------------- fp32 -> bf16 weight convert + LN1 (merged) ----------------
__global__ __launch_bounds__(256) void cvt_ln(
    const float* __restrict__ wq, const float* __restrict__ wk,
    const float* __restrict__ wv, const float* __restrict__ wo,
    const float* __restrict__ w1, const float* __restrict__ w2,
    bf16_t* __restrict__ wqkv, bf16_t* __restrict__ wob, bf16_t* __restrict__ w1b,
    bf16_t* __restrict__ w2b, const float* __restrict__ x, bf16_t* __restrict__ xn,
    const float* __restrict__ gamma, const float* __restrict__ beta) {
    const int b = blockIdx.x, t = threadIdx.x;
    if (b < 12288) {
        const float* in;
        bf16_t* out;
        int i;
        if (b < 1024) { in = wq; out = wqkv; i = b * 256 + t; }
        else if (b < 2048) { in = wk; out = wqkv + 1048576; i = (b - 1024) * 256 + t; }
        else if (b < 3072) { in = wv; out = wqkv + 2097152; i = (b - 2048) * 256 + t; }
        else if (b < 4096) { in = wo; out = wob; i = (b - 3072) * 256 + t; }
        else if (b < 8192) { in = w1; out = w1b; i = (b - 4096) * 256 + t; }
        else { in = w2; out = w2b; i = (b - 8192) * 256 + t; }
        float4 v = ((const float4*)in)[i];
        bf16x4 o = {(__bf16)v.x, (__bf16)v.y, (__bf16)v.z, (__bf16)v.w};
        ((bf16x4*)out)[i] = o;
        return;
    }
    // LN1 over rows (b-12288)*4 .. +3
    const int lane = t & 63;
    const int row = (b - 12288) * 4 + (t >> 6);
    const float* xr = x + (size_t)row * 1024;
    float4 v[4];
    float s = 0.f;
#pragma unroll
    for (int i = 0; i < 4; ++i) {
        v[i] = ((const float4*)xr)[i * 64 + lane];
        s += v[i].x + v[i].y + v[i].z + v[i].w;
    }
#pragma unroll
    for (int o = 32; o; o >>= 1) s += __shfl_xor(s, o);
    float mean = s * (1.f / 1024.f);
    float vs = 0.f;
#pragma unroll
    for (int i = 0; i < 4; ++i) {
        float a = v[i].x - mean, bb2 = v[i].y - mean, c = v[i].z - mean, d = v[i].w - mean;
        vs += a * a + bb2 * bb2 + c * c + d * d;
    }
#pragma unroll
    for (int o = 32; o; o >>= 1) vs += __shfl_xor(vs, o);
    float inv = 1.f / (sqrtf(vs * (1.f / 1023.f)) + 1e-5f);
    float g = gamma[0] * inv, bb = beta[0];
    bf16_t* orow = xn + (size_t)row * 1024;
#pragma unroll
    for (int i = 0; i < 4; ++i) {
        bf16x4 ov = {(__bf16)((v[i].x - mean) * g + bb), (__bf16)((v[i].y - mean) * g + bb),
                     (__bf16)((v[i].z - mean) * g + bb), (__bf16)((v[i].w - mean) * g + bb)};
        *(bf16x4*)(orow + (i * 64 + lane) * 4) = ov;
    }
}

// --------------------------- LayerNorm (torch-style) ------------------------
__global__ __launch_bounds__(256) void ln_kernel(const float* __restrict__ x,
                                                 bf16_t* __restrict__ out,
                                                 const float* __restrict__ gamma,
                                                 const float* __restrict__ beta) {
    const int lane = threadIdx.x & 63;
    const int row = blockIdx.x * 4 + (threadIdx.x >> 6);
    const float* xr = x + (size_t)row * 1024;
    float4 v[4];
    float s = 0.f;
#pragma unroll
    for (int i = 0; i < 4; ++i) {
        v[i] = ((const float4*)xr)[i * 64 + lane];
        s += v[i].x + v[i].y + v[i].z + v[i].w;
    }
#pragma unroll
    for (int o = 32; o; o >>= 1) s += __shfl_xor(s, o);
    float mean = s * (1.f / 1024.f);
    float vs = 0.f;
#pragma unroll
    for (int i = 0; i < 4; ++i) {
        float a = v[i].x - mean, b = v[i].y - mean, c = v[i].z - mean, d = v[i].w - mean;
        vs += a * a + b * b + c * c + d * d;
    }
#pragma unroll
    for (int o = 32; o; o >>= 1) vs += __shfl_xor(vs, o);
    float inv = 1.f / (sqrtf(vs * (1.f / 1023.f)) + 1e-5f);
    float g = gamma[0] * inv, bb = beta[0];
    bf16_t* orow = out + (size_t)row * 1024;
#pragma unroll
    for (int i = 0; i < 4; ++i) {
        bf16x4 ov = {(__bf16)((v[i].x - mean) * g + bb), (__bf16)((v[i].y - mean) * g + bb),
                     (__bf16)((v[i].z - mean) * g + bb), (__bf16)((v[i].w - mean) * g + bb)};
        *(bf16x4*)(orow + (i * 64 + lane) * 4) = ov;
    }
}

// ------------------- Pipelined 256x256 GEMM (C = A @ W^T) -------------------
// 8 waves (2M x 4N), BK=32, 4-slot LDS ring, lookahead 3, counted vmcnt.
template <int KERN>
__global__ __launch_bounds__(512, 2) void gemm256(
    const bf16_t* __restrict__ A, const bf16_t* __restrict__ Bw, int K,
    const float* __restrict__ bias0, const float* __restrict__ bias1,
    const float* __restrict__ bias2, void* __restrict__ o0, void* __restrict__ o1,
    void* __restrict__ o2) {
    __shared__ bf16_t L[4 * 16384];  // 4 slots x (A 256x32 + B 256x32) = 128KB
    const int t = threadIdx.x, lane = t & 63, w = t >> 6;
    const int wm = w >> 2, wn = w & 3;
    const int l15 = lane & 15, l4 = lane >> 4;
    const int bm = blockIdx.x, bn = blockIdx.y;
    const int NT = K >> 5;
    const bf16_t* Ab = A + (size_t)bm * 256 * K;
    const bf16_t* Bb = Bw + (size_t)bn * 256 * K;
    const int srow = t >> 2, pcol = (t & 3) * 8;
    f32x4 acc[8][4] = {};

    auto stageA = [&](int tt) {
        bf16_t* s = L + (tt & 3) * 16384;
        const int kb = tt * 32;
#pragma unroll
        for (int i = 0; i < 2; ++i) {
            int row = i * 128 + srow;
            int lcol = pcol ^ bswz(row);
            gload_lds16(Ab + (size_t)row * K + kb + lcol, s + i * 4096 + t * 8);
        }
    };
    auto stageB = [&](int tt) {
        bf16_t* s = L + (tt & 3) * 16384 + 8192;
        const int kb = tt * 32;
#pragma unroll
        for (int i = 0; i < 2; ++i) {
            int row = i * 128 + srow;
            int lcol = pcol ^ bswz(row);
            gload_lds16(Bb + (size_t)row * K + kb + lcol, s + i * 4096 + t * 8);
        }
    };

    stageA(0); stageB(0); stageA(1); stageB(1); stageA(2); stageB(2);
    asm volatile("s_waitcnt vmcnt(8)" ::: "memory");
    __builtin_amdgcn_s_barrier();

    for (int tt = 0; tt < NT; ++tt) {
        bf16_t* s = L + (tt & 3) * 16384;
        bf16_t* sB = s + 8192;
        bf16x8 af[4], bfr[4];
#pragma unroll
        for (int m = 0; m < 4; ++m) {
            int row = wm * 128 + m * 16 + l15;
            af[m] = *(const bf16x8*)(s + row * 32 + ((l4 * 8) ^ bswz(row)));
        }
#pragma unroll
        for (int n = 0; n < 4; ++n) {
            int row = wn * 64 + n * 16 + l15;
            bfr[n] = *(const bf16x8*)(sB + row * 32 + ((l4 * 8) ^ bswz(row)));
        }
        if (tt + 3 < NT) stageA(tt + 3);
        __builtin_amdgcn_s_barrier();
        __builtin_amdgcn_s_setprio(1);
#pragma unroll
        for (int m = 0; m < 4; ++m)
#pragma unroll
            for (int n = 0; n < 4; ++n)
                acc[m][n] = __builtin_amdgcn_mfma_f32_16x16x32_bf16(af[m], bfr[n], acc[m][n],
                                                                   0, 0, 0);
        __builtin_amdgcn_s_setprio(0);
        __builtin_amdgcn_s_barrier();
#pragma unroll
        for (int m = 0; m < 4; ++m) {
            int row = wm * 128 + 64 + m * 16 + l15;
            af[m] = *(const bf16x8*)(s + row * 32 + ((l4 * 8) ^ bswz(row)));
        }
        if (tt + 3 < NT) stageB(tt + 3);
        __builtin_amdgcn_s_barrier();
        __builtin_amdgcn_s_setprio(1);
#pragma unroll
        for (int m = 0; m < 4; ++m)
#pragma unroll
            for (int n = 0; n < 4; ++n)
                acc[4 + m][n] = __builtin_amdgcn_mfma_f32_16x16x32_bf16(af[m], bfr[n],
                                                                       acc[4 + m][n], 0, 0, 0);
        __builtin_amdgcn_s_setprio(0);
        if (tt + 3 < NT)
            asm volatile("s_waitcnt vmcnt(8)" ::: "memory");
        else if (tt + 2 < NT)
            asm volatile("s_waitcnt vmcnt(4)" ::: "memory");
        else
            asm volatile("s_waitcnt vmcnt(0)" ::: "memory");
        __builtin_amdgcn_s_barrier();
    }

    if (KERN == 1) {
        const int colb = bn * 256 + wn * 64;
        float bb[4];
#pragma unroll
        for (int n = 0; n < 4; ++n) bb[n] = bias0[colb + n * 16 + l15];
#pragma unroll
        for (int m = 0; m < 8; ++m) {
            const int row0 = bm * 256 + wm * 128 + m * 16 + (l4 << 2);
#pragma unroll
            for (int n = 0; n < 4; ++n)
#pragma unroll
                for (int j = 0; j < 4; ++j) {
                    float v = acc[m][n][j] + bb[n];
                    ((bf16_t*)o0)[(size_t)(row0 + j) * 4096 + colb + n * 16 + l15] =
                        (bf16_t)(v > 0.f ? v : 0.f);
                }
        }
        return;
    }
    // KERN 0: QKV
    if (bn < 8) {
        const bool isq = bn < 4;
        const float* bias = isq ? bias0 : bias1;
        const int head = (bn & 3) * 4 + wn;
        const int b = (bm * 256) >> 11;
        const int srow0 = (bm * 256 + wm * 128) & 2047;
        bf16_t* dst = (bf16_t*)(isq ? o0 : o1) + ((size_t)(b * 16 + head) << 17);
        float bb[4];
#pragma unroll
        for (int n = 0; n < 4; ++n) bb[n] = bias[head * 64 + n * 16 + l15];
#pragma unroll
        for (int m = 0; m < 8; ++m)
#pragma unroll
            for (int n = 0; n < 4; ++n)
#pragma unroll
                for (int j = 0; j < 4; ++j) {
                    int srw = srow0 + m * 16 + (l4 << 2) + j;
                    float v = acc[m][n][j] + bb[n];
                    if (isq) v *= QSCALE;
                    dst[((size_t)srw << 6) + n * 16 + l15] = (bf16_t)v;
                }
    } else {
        // v: per-wave LDS transpose -> [B,H,64,S] coalesced
        const int head = (bn - 8) * 4 + wn;
        const int b = (bm * 256) >> 11;
        const int sbase = (bm * 256 + wm * 128) & 2047;
        bf16_t* P = L + w * 8192;
        float bb[4];
#pragma unroll
        for (int n = 0; n < 4; ++n) bb[n] = bias2[head * 64 + n * 16 + l15];
#pragma unroll
        for (int m = 0; m < 8; ++m)
#pragma unroll
            for (int n = 0; n < 4; ++n) {
                int d = n * 16 + l15;
                int sl = m * 16 + (l4 << 2);
                bf16x4 pk = {(__bf16)(acc[m][n][0] + bb[n]), (__bf16)(acc[m][n][1] + bb[n]),
                             (__bf16)(acc[m][n][2] + bb[n]), (__bf16)(acc[m][n][3] + bb[n])};
                *(bf16x4*)(P + d * 128 + (sl ^ ((d & 7) << 3))) = pk;
            }
#pragma unroll
        for (int p = 0; p < 16; ++p) {
            int id = p * 64 + lane;
            int d = id >> 4, c8 = (id & 15) * 8;
            bf16x8 vv = *(const bf16x8*)(P + d * 128 + (c8 ^ ((d & 7) << 3)));
            *(bf16x8*)((bf16_t*)o2 + (((size_t)(b * 16 + head) * 64 + d) << 11) + sbase + c8) =
                vv;
        }
    }
}

// ------------- Pipelined 128x128 GEMM, wave=64x64 (C = A @ W^T) -------------
// 4-slot ring, lookahead 3, counted vmcnt. SPLIT=0: +bias +resid -> fp32.
// SPLIT=1: K-split via blockIdx.z, raw partial -> bf16.
template <int SPLIT>
__global__ __launch_bounds__(256, 2) void gemm128sq(
    const bf16_t* __restrict__ A, const bf16_t* __restrict__ Bw, int stride, int Ks,
    const float* __restrict__ bias, const float* __restrict__ resid,
    void* __restrict__ o0, void* __restrict__ o1) {
    __shared__ bf16_t L[4 * 8192];  // 4 slots x (A 128x32 + B 128x32) = 64KB
    const int t = threadIdx.x, lane = t & 63, w = t >> 6;
    const int wr = w >> 1, wc = w & 1;
    const int l15 = lane & 15, l4 = lane >> 4;
    const int bm = blockIdx.x, bn = blockIdx.y;
    const int NT = Ks >> 5;
    const size_t kofs = SPLIT ? (size_t)blockIdx.z * Ks : 0;
    const bf16_t* Ab = A + (size_t)bm * 128 * stride + kofs;
    const bf16_t* Bb = Bw + (size_t)bn * 128 * stride + kofs;
    const int srow = t >> 2, pcol = (t & 3) * 8;
    f32x4 acc[4][4] = {};

    auto STAGE = [&](int tt) {
        bf16_t* s = L + (tt & 3) * 8192;
        const int kb = tt * 32;
#pragma unroll
        for (int i = 0; i < 2; ++i) {
            int row = i * 64 + srow;
            int lcol = pcol ^ bswz(row);
            gload_lds16(Ab + (size_t)row * stride + kb + lcol, s + i * 2048 + t * 8);
            gload_lds16(Bb + (size_t)row * stride + kb + lcol, s + 4096 + i * 2048 + t * 8);
        }
    };

    STAGE(0); STAGE(1); STAGE(2);
    asm volatile("s_waitcnt vmcnt(8)" ::: "memory");
    __builtin_amdgcn_s_barrier();

    for (int tt = 0; tt < NT; ++tt) {
        bf16_t* s = L + (tt & 3) * 8192;
        bf16x8 af[4], bfr[4];
#pragma unroll
        for (int m = 0; m < 4; ++m) {
            int row = wr * 64 + m * 16 + l15;
            af[m] = *(const bf16x8*)(s + row * 32 + ((l4 * 8) ^ bswz(row)));
        }
#pragma unroll
        for (int n = 0; n < 4; ++n) {
            int row = wc * 64 + n * 16 + l15;
            bfr[n] = *(const bf16x8*)(s + 4096 + row * 32 + ((l4 * 8) ^ bswz(row)));
        }
        if (tt + 3 < NT) STAGE(tt + 3);
        __builtin_amdgcn_s_barrier();
        __builtin_amdgcn_s_setprio(1);
#pragma unroll
        for (int m = 0; m < 4; ++m)
#pragma unroll
            for (int n = 0; n < 4; ++n)
                acc[m][n] = __builtin_amdgcn_mfma_f32_16x16x32_bf16(af[m], bfr[n], acc[m][n],
                                                                   0, 0, 0);
        __builtin_amdgcn_s_setprio(0);
        if (tt + 3 < NT)
            asm volatile("s_waitcnt vmcnt(8)" ::: "memory");
        else if (tt + 2 < NT)
            asm volatile("s_waitcnt vmcnt(4)" ::: "memory");
        else
            asm volatile("s_waitcnt vmcnt(0)" ::: "memory");
        __builtin_amdgcn_s_barrier();
    }

#pragma unroll
    for (int m = 0; m < 4; ++m) {
        const int row0 = bm * 128 + wr * 64 + m * 16 + (l4 << 2);
#pragma unroll
        for (int n = 0; n < 4; ++n) {
            const int col = bn * 128 + wc * 64 + n * 16 + l15;
#pragma unroll
            for (int j = 0; j < 4; ++j) {
                const int row = row0 + j;
                if (SPLIT == 0) {
                    ((float*)o0)[(size_t)row * 1024 + col] =
                        resid[(size_t)row * 1024 + col] + acc[m][n][j] + bias[col];
                } else {
                    bf16_t* po = (bf16_t*)(blockIdx.z ? o1 : o0);
                    po[(size_t)row * 1024 + col] = (bf16_t)acc[m][n][j];
                }
            }
        }
    }
}

// ---- FFN2 combine: out = p0 + p1 + resid + bias (fp32), 4096x1024 ----------
__global__ __launch_bounds__(256) void ffn2_combine(
    const bf16_t* __restrict__ p0, const bf16_t* __restrict__ p1,
    const float* __restrict__ resid, const float* __restrict__ bias,
    float* __restrict__ out) {
    int i = blockIdx.x * 256 + threadIdx.x;  // float4 index, 1M total
    float4 r = ((const float4*)resid)[i];
    bf16x4 a = ((const bf16x4*)p0)[i];
    bf16x4 b = ((const bf16x4*)p1)[i];
    float4 bs = ((const float4*)bias)[i & 255];
    float4 o;
    o.x = r.x + (float)a.x + (float)b.x + bs.x;
    o.y = r.y + (float)a.y + (float)b.y + bs.y;
    o.z = r.z + (float)a.z + (float)b.z + bs.z;
    o.w = r.w + (float)a.w + (float)b.w + bs.w;
    ((float4*)out)[i] = o;
}

// --------------------------- Flash attention (R15) --------------------------
// Single kernel, grid 512, XCD-swizzled. 4 waves x 32 q-rows, KVBLK=64.
// T15 double-pipeline: QK(t) MFMA overlaps softmax+PV of tile t-1.
// 2-slot LDS, reg-staged prefetch, 2 barriers/iter (same as R8).
__global__ __launch_bounds__(256, 2) void attn_kernel(const bf16_t* __restrict__ q,
                                                      const bf16_t* __restrict__ k,
                                                      const bf16_t* __restrict__ vt,
                                                      bf16_t* __restrict__ ctx) {
    __shared__ bf16_t Kl[2][64 * 64];
    __shared__ bf16_t Vl[2][64 * 64];
    const int t = threadIdx.x, lane = t & 63, w = t >> 6;
    const int bid = blockIdx.x;
    const int xcd = bid & 7, j = bid >> 3;
    const int bh = xcd + ((j >> 4) << 3);
    const int qx = j & 15;
    const bf16_t* qg = q + (size_t)bh * 2048 * 64;
    const bf16_t* kg = k + (size_t)bh * 2048 * 64;
    const bf16_t* vg = vt + (size_t)bh * 64 * 2048;
    const int r = t >> 3, c8 = (t & 7) * 8;
    const int l31 = lane & 31, h = lane >> 5;
    const int qrow = qx * 128 + w * 32 + l31;

    bf16x8 qf[4];
#pragma unroll
    for (int kd = 0; kd < 4; ++kd)
        qf[kd] = *(const bf16x8*)(qg + (size_t)qrow * 64 + kd * 16 + h * 8);

    f32x16 o0 = {}, o1 = {};
    float mi = -1e30f, li = 0.f;
    f32x16 p0, p1;  // previous tile's scores (T15 second pipeline stage)

    // softmax + PV for a completed score tile (reads Vb, updates o/mi/li)
    auto SMPV = [&](f32x16& e0, f32x16& e1, const bf16_t* Vb) {
        float pm[16];
#pragma unroll
        for (int i = 0; i < 16; ++i) pm[i] = fmaxf(e0[i], e1[i]);
#pragma unroll
        for (int st = 8; st; st >>= 1)
#pragma unroll
            for (int i = 0; i < st; ++i) pm[i] = fmaxf(pm[i], pm[i + st]);
        float mx = fmaxf(pm[0], __shfl_xor(pm[0], 32));
        if (!__all(mx <= mi + 8.f)) {
            float mn = fmaxf(mi, mx);
            float al = __builtin_amdgcn_exp2f(mi - mn);
            mi = mn;
            li *= al;
            o0 *= al;
            o1 *= al;
        }
#pragma unroll
        for (int i = 0; i < 16; ++i) e0[i] = __builtin_amdgcn_exp2f(e0[i] - mi);
#pragma unroll
        for (int i = 0; i < 16; ++i) e1[i] = __builtin_amdgcn_exp2f(e1[i] - mi);
        float ps[16];
#pragma unroll
        for (int i = 0; i < 16; ++i) ps[i] = e0[i] + e1[i];
#pragma unroll
        for (int st = 8; st; st >>= 1)
#pragma unroll
            for (int i = 0; i < st; ++i) ps[i] += ps[i + st];
        li += ps[0] + __shfl_xor(ps[0], 32);
        bf16x8 pa[4];
#pragma unroll
        for (int kd = 0; kd < 4; ++kd) {
            const f32x16& e = (kd < 2) ? e0 : e1;
            const int R0l = 8 * (kd & 1);
            const int R0h = R0l + 4;
            unsigned U0 = cvtpk(e[R0l + 0], e[R0l + 1]);
            unsigned V0 = cvtpk(e[R0l + 2], e[R0l + 3]);
            unsigned U1 = cvtpk(e[R0h + 0], e[R0h + 1]);
            unsigned V1 = cvtpk(e[R0h + 2], e[R0h + 3]);
            uint32x2 ru = __builtin_amdgcn_permlane32_swap(U0, U1, false, false);
            uint32x2 rv = __builtin_amdgcn_permlane32_swap(V0, V1, false, false);
            uint32x4 pw = {ru.x, rv.x, ru.y, rv.y};
            pa[kd] = __builtin_bit_cast(bf16x8, pw);
        }
        __builtin_amdgcn_s_setprio(1);
#pragma unroll
        for (int kd = 0; kd < 4; ++kd) {
            bf16x8 va0 = *(const bf16x8*)(Vb + swz(l31, kd * 16 + h * 8));
            bf16x8 va1 = *(const bf16x8*)(Vb + swz(32 + l31, kd * 16 + h * 8));
            o0 = __builtin_amdgcn_mfma_f32_32x32x16_bf16(va0, pa[kd], o0, 0, 0, 0);
            o1 = __builtin_amdgcn_mfma_f32_32x32x16_bf16(va1, pa[kd], o1, 0, 0, 0);
        }
        __builtin_amdgcn_s_setprio(0);
    };

    // prologue: stage tile 0 into slot 0
    {
        bf16x8 k0 = *(const bf16x8*)(kg + (size_t)r * 64 + c8);
        bf16x8 k1 = *(const bf16x8*)(kg + (size_t)(r + 32) * 64 + c8);
        bf16x8 v0 = *(const bf16x8*)(vg + (size_t)r * 2048 + c8);
        bf16x8 v1 = *(const bf16x8*)(vg + (size_t)(r + 32) * 2048 + c8);
        *(bf16x8*)(&Kl[0][swz(r, c8)]) = k0;
        *(bf16x8*)(&Kl[0][swz(r + 32, c8)]) = k1;
        *(bf16x8*)(&Vl[0][swz(r, c8)]) = v0;
        *(bf16x8*)(&Vl[0][swz(r + 32, c8)]) = v1;
    }
    __syncthreads();

    const int NT = 32;
    for (int tt = 0; tt < NT; ++tt) {
        // prefetch next tile into regs
        bf16x8 k0, k1, v0, v1;
        const bool more = (tt + 1) < NT;
        if (more) {
            const int kb = (tt + 1) * 64;
            k0 = *(const bf16x8*)(kg + (size_t)(kb + r) * 64 + c8);
            k1 = *(const bf16x8*)(kg + (size_t)(kb + r + 32) * 64 + c8);
            v0 = *(const bf16x8*)(vg + (size_t)r * 2048 + kb + c8);
            v1 = *(const bf16x8*)(vg + (size_t)(r + 32) * 2048 + kb + c8);
        }
        // QK^T(tt) from Kl[tt&1] (MFMA pipe; overlaps SMPV's VALU/trans below)
        const bf16_t* Kb = Kl[tt & 1];
        f32x16 sT0 = {}, sT1 = {};
        __builtin_amdgcn_s_setprio(1);
#pragma unroll
        for (int kd = 0; kd < 4; ++kd) {
            bf16x8 ka0 = *(const bf16x8*)(Kb + swz(l31, kd * 16 + h * 8));
            bf16x8 ka1 = *(const bf16x8*)(Kb + swz(32 + l31, kd * 16 + h * 8));
            sT0 = __builtin_amdgcn_mfma_f32_32x32x16_bf16(ka0, qf[kd], sT0, 0, 0, 0);
            sT1 = __builtin_amdgcn_mfma_f32_32x32x16_bf16(ka1, qf[kd], sT1, 0, 0, 0);
        }
        __builtin_amdgcn_s_setprio(0);
        // softmax + PV of PREVIOUS tile (tile tt-1, V in slot (tt-1)&1)
        if (tt > 0) SMPV(p0, p1, Vl[(tt - 1) & 1]);
        p0 = sT0;
        p1 = sT1;
        __syncthreads();  // all reads of Kl[tt&1] (QK) and Vl[(tt-1)&1] (PV) done
        if (more) {
            bf16_t* kd_ = Kl[(tt + 1) & 1];
            bf16_t* vd_ = Vl[(tt + 1) & 1];
            *(bf16x8*)(&kd_[swz(r, c8)]) = k0;
            *(bf16x8*)(&kd_[swz(r + 32, c8)]) = k1;
            *(bf16x8*)(&vd_[swz(r, c8)]) = v0;
            *(bf16x8*)(&vd_[swz(r + 32, c8)]) = v1;
        }
        __syncthreads();  // staged tile visible for next iteration
    }
    // drain: softmax + PV for the last tile (V in slot (NT-1)&1 = 1)
    SMPV(p0, p1, Vl[1]);

    // epilogue: direct ctx write (lane-local 1/l)
    float inv = 1.f / li;
    size_t base = ((size_t)(bh >> 4) * 2048 + qrow) * 1024 + (bh & 15) * 64;
#pragma unroll
    for (int g = 0; g < 4; ++g) {
        bf16x4 ov0 = {(__bf16)(o0[4 * g + 0] * inv), (__bf16)(o0[4 * g + 1] * inv),
                      (__bf16)(o0[4 * g + 2] * inv), (__bf16)(o0[4 * g + 3] * inv)};
        *(bf16x4*)(ctx + base + 8 * g + 4 * h) = ov0;
        bf16x4 ov1 = {(__bf16)(o1[4 * g + 0] * inv), (__bf16)(o1[4 * g + 1] * inv),
                      (__bf16)(o1[4 * g + 2] * inv), (__bf16)(o1[4 * g + 3] * inv)};
        *(bf16x4*)(ctx + base + 32 + 8 * g + 4 * h) = ov1;
    }
}

// ---------------------------------------------------------------------------
extern "C" void kernel_launch(void* const* d_in, const int* in_sizes, int n_in,
                              void* d_out, int out_size, void* d_ws, size_t ws_size,
                              hipStream_t stream) {
    const float* x = (const float*)d_in[0];
    const float* wq = (const float*)d_in[2];
    const float* bq = (const float*)d_in[3];
    const float* wk = (const float*)d_in[4];
    const float* bk = (const float*)d_in[5];
    const float* wv = (const float*)d_in[6];
    const float* bv = (const float*)d_in[7];
    const float* wo = (const float*)d_in[8];
    const float* bo = (const float*)d_in[9];
    const float* w1 = (const float*)d_in[10];
    const float* b1 = (const float*)d_in[11];
    const float* w2 = (const float*)d_in[12];
    const float* b2 = (const float*)d_in[13];
    const float* gamma1 = (const float*)d_in[14];
    const float* beta1 = (const float*)d_in[15];
    const float* gamma2 = (const float*)d_in[16];
    const float* beta2 = (const float*)d_in[17];

    char* ws = (char*)d_ws;
    bf16_t* wqkv = (bf16_t*)(ws + 0);
    bf16_t* wob = (bf16_t*)(ws + 6 * MB);
    bf16_t* w1b = (bf16_t*)(ws + 8 * MB);
    bf16_t* w2b = (bf16_t*)(ws + 16 * MB);
    bf16_t* xnb = (bf16_t*)(ws + 24 * MB);
    bf16_t* qb = (bf16_t*)(ws + 32 * MB);
    bf16_t* kb = (bf16_t*)(ws + 40 * MB);
    bf16_t* vtb = (bf16_t*)(ws + 48 * MB);
    bf16_t* ctxb = (bf16_t*)(ws + 56 * MB);
    float* x1 = (float*)(ws + 64 * MB);
    bf16_t* hb = (bf16_t*)(ws + 32 * MB);  // reuses q/k/vT/ctx (dead by FFN1)
    bf16_t* p0 = (bf16_t*)(ws + 0);        // FFN2 partial z=0 (wqkv/wob dead)
    bf16_t* p1 = (bf16_t*)(ws + 24 * MB);  // FFN2 partial z=1 (xnb dead)

    // weight converts + LN1 (merged)
    cvt_ln<<<13312, 256, 0, stream>>>(wq, wk, wv, wo, w1, w2, wqkv, wob, w1b, w2b, x, xnb,
                                      gamma1, beta1);
    // QKV fused GEMM (256x256, N=3072)
    gemm256<0><<<dim3(16, 12), 512, 0, stream>>>(xnb, wqkv, 1024, bq, bk, bv, qb, kb, vtb);
    // attention (single kernel, XCD-swizzled, T15 double-pipeline)
    attn_kernel<<<512, 256, 0, stream>>>(qb, kb, vtb, ctxb);
    // out-proj + residual -> x1 (fp32)
    gemm128sq<0><<<dim3(32, 8), 256, 0, stream>>>(ctxb, wob, 1024, 1024, bo, x, x1, nullptr);
    // LN2
    ln_kernel<<<1024, 256, 0, stream>>>(x1, xnb, gamma2, beta2);
    // FFN1 + relu (256x256, N=4096)
    gemm256<1><<<dim3(16, 16), 512, 0, stream>>>(xnb, w1b, 1024, b1, nullptr, nullptr, hb,
                                                 nullptr, nullptr);
    // FFN2 K-split-2 -> bf16 partials, then combine with residual -> d_out
    gemm128sq<1><<<dim3(32, 8, 2), 256, 0, stream>>>(hb, w2b, 4096, 2048, nullptr, nullptr,
                                                     p0, p1);
    ffn2_combine<<<4096, 256, 0, stream>>>(p0, p1, x1, b2, (float*)d_out);
}

// Round 16
// 210.929 us; speedup vs baseline: 1.0211x; 1.0211x over previous
//
#include <hip/hip_runtime.h>

// ---------------------------------------------------------------------------
// EncoderBlock: pre-LN transformer block, B=2 S=2048 D=1024 H=16 dk=64 F=4096
// R16: final consolidation — every component at its best-measured config:
//     attention = R8 core VERBATIM (60.6us: reg-staged single-buffer KVBLK=64,
//     XCD-swizzled grid 512, swapped QK^T+PV, lane-local softmax, P in regs);
//     cvt+LN1 merged launch (R15); GEMMs = 4-slot/lookahead-3 (R13);
//     FFN2 K-split-2 + combine.
// Workspace layout (80 MB used):
//   [0,6M)    wqkv bf16 (dead after QKV) -> p0 bf16 for FFN2
//   [6M,8M)   wo bf16
//   [8M,16M)  w1 bf16
//   [16M,24M) w2 bf16
//   [24M,32M) xn bf16 (LN out; dead after FFN1) -> p1 bf16 for FFN2
//   [32M,40M) q bf16 [B,H,S,64] (scaled by 0.125*log2e)  } reused as h for FFN1
//   [40M,48M) k bf16 [B,H,S,64]                          }
//   [48M,56M) vT bf16 [B,H,64,S]                         }
//   [56M,64M) ctx bf16 flat [B*S,1024]                   }
//   [64M,80M) x1 fp32 (residual after attention)
// ---------------------------------------------------------------------------

typedef __bf16 bf16_t;
typedef __attribute__((ext_vector_type(8))) __bf16 bf16x8;
typedef __attribute__((ext_vector_type(4))) __bf16 bf16x4;
typedef __attribute__((ext_vector_type(2))) __bf16 bf16x2;
typedef __attribute__((ext_vector_type(4))) float f32x4;
typedef __attribute__((ext_vector_type(16))) float f32x16;
typedef __attribute__((ext_vector_type(2))) unsigned uint32x2;
typedef __attribute__((ext_vector_type(4))) unsigned uint32x4;

#define MB (1024ull * 1024ull)
#define QSCALE 0.18033688011112043f /* 0.125 * log2(e) */

__device__ __forceinline__ void gload_lds16(const bf16_t* g, bf16_t* l) {
    __builtin_amdgcn_global_load_lds(
        (const __attribute__((address_space(1))) void*)g,
        (__attribute__((address_space(3))) void*)l, 16, 0, 0);
}

// Bank-slot XOR for BK=32 (64B) LDS rows: slot ^= (row>>1)&3 (2-way max).
__device__ __forceinline__ int bswz(int row) { return ((row >> 1) & 3) << 3; }

// XOR swizzle for 64-col bf16 LDS tiles (128B rows, 8 chunks).
__device__ __forceinline__ int swz(int row, int col) {
    return row * 64 + ((((col >> 3) ^ row) & 7) << 3) + (col & 7);
}

__device__ __forceinline__ unsigned cvtpk(float a, float b) {
    bf16x2 v = {(__bf16)a, (__bf16)b};
    return __builtin_bit_cast(unsigned, v);
}

// ---------------- fp32 -> bf16 weight convert + LN1 (merged) ----------------
__global__ __launch_bounds__(256) void cvt_ln(
    const float* __restrict__ wq, const float* __restrict__ wk,
    const float* __restrict__ wv, const float* __restrict__ wo,
    const float* __restrict__ w1, const float* __restrict__ w2,
    bf16_t* __restrict__ wqkv, bf16_t* __restrict__ wob, bf16_t* __restrict__ w1b,
    bf16_t* __restrict__ w2b, const float* __restrict__ x, bf16_t* __restrict__ xn,
    const float* __restrict__ gamma, const float* __restrict__ beta) {
    const int b = blockIdx.x, t = threadIdx.x;
    if (b < 12288) {
        const float* in;
        bf16_t* out;
        int i;
        if (b < 1024) { in = wq; out = wqkv; i = b * 256 + t; }
        else if (b < 2048) { in = wk; out = wqkv + 1048576; i = (b - 1024) * 256 + t; }
        else if (b < 3072) { in = wv; out = wqkv + 2097152; i = (b - 2048) * 256 + t; }
        else if (b < 4096) { in = wo; out = wob; i = (b - 3072) * 256 + t; }
        else if (b < 8192) { in = w1; out = w1b; i = (b - 4096) * 256 + t; }
        else { in = w2; out = w2b; i = (b - 8192) * 256 + t; }
        float4 v = ((const float4*)in)[i];
        bf16x4 o = {(__bf16)v.x, (__bf16)v.y, (__bf16)v.z, (__bf16)v.w};
        ((bf16x4*)out)[i] = o;
        return;
    }
    // LN1 over rows (b-12288)*4 .. +3
    const int lane = t & 63;
    const int row = (b - 12288) * 4 + (t >> 6);
    const float* xr = x + (size_t)row * 1024;
    float4 v[4];
    float s = 0.f;
#pragma unroll
    for (int i = 0; i < 4; ++i) {
        v[i] = ((const float4*)xr)[i * 64 + lane];
        s += v[i].x + v[i].y + v[i].z + v[i].w;
    }
#pragma unroll
    for (int o = 32; o; o >>= 1) s += __shfl_xor(s, o);
    float mean = s * (1.f / 1024.f);
    float vs = 0.f;
#pragma unroll
    for (int i = 0; i < 4; ++i) {
        float a = v[i].x - mean, bb2 = v[i].y - mean, c = v[i].z - mean, d = v[i].w - mean;
        vs += a * a + bb2 * bb2 + c * c + d * d;
    }
#pragma unroll
    for (int o = 32; o; o >>= 1) vs += __shfl_xor(vs, o);
    float inv = 1.f / (sqrtf(vs * (1.f / 1023.f)) + 1e-5f);
    float g = gamma[0] * inv, bb = beta[0];
    bf16_t* orow = xn + (size_t)row * 1024;
#pragma unroll
    for (int i = 0; i < 4; ++i) {
        bf16x4 ov = {(__bf16)((v[i].x - mean) * g + bb), (__bf16)((v[i].y - mean) * g + bb),
                     (__bf16)((v[i].z - mean) * g + bb), (__bf16)((v[i].w - mean) * g + bb)};
        *(bf16x4*)(orow + (i * 64 + lane) * 4) = ov;
    }
}

// --------------------------- LayerNorm (torch-style) ------------------------
__global__ __launch_bounds__(256) void ln_kernel(const float* __restrict__ x,
                                                 bf16_t* __restrict__ out,
                                                 const float* __restrict__ gamma,
                                                 const float* __restrict__ beta) {
    const int lane = threadIdx.x & 63;
    const int row = blockIdx.x * 4 + (threadIdx.x >> 6);
    const float* xr = x + (size_t)row * 1024;
    float4 v[4];
    float s = 0.f;
#pragma unroll
    for (int i = 0; i < 4; ++i) {
        v[i] = ((const float4*)xr)[i * 64 + lane];
        s += v[i].x + v[i].y + v[i].z + v[i].w;
    }
#pragma unroll
    for (int o = 32; o; o >>= 1) s += __shfl_xor(s, o);
    float mean = s * (1.f / 1024.f);
    float vs = 0.f;
#pragma unroll
    for (int i = 0; i < 4; ++i) {
        float a = v[i].x - mean, b = v[i].y - mean, c = v[i].z - mean, d = v[i].w - mean;
        vs += a * a + b * b + c * c + d * d;
    }
#pragma unroll
    for (int o = 32; o; o >>= 1) vs += __shfl_xor(vs, o);
    float inv = 1.f / (sqrtf(vs * (1.f / 1023.f)) + 1e-5f);
    float g = gamma[0] * inv, bb = beta[0];
    bf16_t* orow = out + (size_t)row * 1024;
#pragma unroll
    for (int i = 0; i < 4; ++i) {
        bf16x4 ov = {(__bf16)((v[i].x - mean) * g + bb), (__bf16)((v[i].y - mean) * g + bb),
                     (__bf16)((v[i].z - mean) * g + bb), (__bf16)((v[i].w - mean) * g + bb)};
        *(bf16x4*)(orow + (i * 64 + lane) * 4) = ov;
    }
}

// ------------------- Pipelined 256x256 GEMM (C = A @ W^T) -------------------
// 8 waves (2M x 4N), BK=32, 4-slot LDS ring, lookahead 3, counted vmcnt.
template <int KERN>
__global__ __launch_bounds__(512, 2) void gemm256(
    const bf16_t* __restrict__ A, const bf16_t* __restrict__ Bw, int K,
    const float* __restrict__ bias0, const float* __restrict__ bias1,
    const float* __restrict__ bias2, void* __restrict__ o0, void* __restrict__ o1,
    void* __restrict__ o2) {
    __shared__ bf16_t L[4 * 16384];  // 4 slots x (A 256x32 + B 256x32) = 128KB
    const int t = threadIdx.x, lane = t & 63, w = t >> 6;
    const int wm = w >> 2, wn = w & 3;
    const int l15 = lane & 15, l4 = lane >> 4;
    const int bm = blockIdx.x, bn = blockIdx.y;
    const int NT = K >> 5;
    const bf16_t* Ab = A + (size_t)bm * 256 * K;
    const bf16_t* Bb = Bw + (size_t)bn * 256 * K;
    const int srow = t >> 2, pcol = (t & 3) * 8;
    f32x4 acc[8][4] = {};

    auto stageA = [&](int tt) {
        bf16_t* s = L + (tt & 3) * 16384;
        const int kb = tt * 32;
#pragma unroll
        for (int i = 0; i < 2; ++i) {
            int row = i * 128 + srow;
            int lcol = pcol ^ bswz(row);
            gload_lds16(Ab + (size_t)row * K + kb + lcol, s + i * 4096 + t * 8);
        }
    };
    auto stageB = [&](int tt) {
        bf16_t* s = L + (tt & 3) * 16384 + 8192;
        const int kb = tt * 32;
#pragma unroll
        for (int i = 0; i < 2; ++i) {
            int row = i * 128 + srow;
            int lcol = pcol ^ bswz(row);
            gload_lds16(Bb + (size_t)row * K + kb + lcol, s + i * 4096 + t * 8);
        }
    };

    stageA(0); stageB(0); stageA(1); stageB(1); stageA(2); stageB(2);
    asm volatile("s_waitcnt vmcnt(8)" ::: "memory");
    __builtin_amdgcn_s_barrier();

    for (int tt = 0; tt < NT; ++tt) {
        bf16_t* s = L + (tt & 3) * 16384;
        bf16_t* sB = s + 8192;
        bf16x8 af[4], bfr[4];
#pragma unroll
        for (int m = 0; m < 4; ++m) {
            int row = wm * 128 + m * 16 + l15;
            af[m] = *(const bf16x8*)(s + row * 32 + ((l4 * 8) ^ bswz(row)));
        }
#pragma unroll
        for (int n = 0; n < 4; ++n) {
            int row = wn * 64 + n * 16 + l15;
            bfr[n] = *(const bf16x8*)(sB + row * 32 + ((l4 * 8) ^ bswz(row)));
        }
        if (tt + 3 < NT) stageA(tt + 3);
        __builtin_amdgcn_s_barrier();
        __builtin_amdgcn_s_setprio(1);
#pragma unroll
        for (int m = 0; m < 4; ++m)
#pragma unroll
            for (int n = 0; n < 4; ++n)
                acc[m][n] = __builtin_amdgcn_mfma_f32_16x16x32_bf16(af[m], bfr[n], acc[m][n],
                                                                   0, 0, 0);
        __builtin_amdgcn_s_setprio(0);
        __builtin_amdgcn_s_barrier();
#pragma unroll
        for (int m = 0; m < 4; ++m) {
            int row = wm * 128 + 64 + m * 16 + l15;
            af[m] = *(const bf16x8*)(s + row * 32 + ((l4 * 8) ^ bswz(row)));
        }
        if (tt + 3 < NT) stageB(tt + 3);
        __builtin_amdgcn_s_barrier();
        __builtin_amdgcn_s_setprio(1);
#pragma unroll
        for (int m = 0; m < 4; ++m)
#pragma unroll
            for (int n = 0; n < 4; ++n)
                acc[4 + m][n] = __builtin_amdgcn_mfma_f32_16x16x32_bf16(af[m], bfr[n],
                                                                       acc[4 + m][n], 0, 0, 0);
        __builtin_amdgcn_s_setprio(0);
        if (tt + 3 < NT)
            asm volatile("s_waitcnt vmcnt(8)" ::: "memory");
        else if (tt + 2 < NT)
            asm volatile("s_waitcnt vmcnt(4)" ::: "memory");
        else
            asm volatile("s_waitcnt vmcnt(0)" ::: "memory");
        __builtin_amdgcn_s_barrier();
    }

    if (KERN == 1) {
        const int colb = bn * 256 + wn * 64;
        float bb[4];
#pragma unroll
        for (int n = 0; n < 4; ++n) bb[n] = bias0[colb + n * 16 + l15];
#pragma unroll
        for (int m = 0; m < 8; ++m) {
            const int row0 = bm * 256 + wm * 128 + m * 16 + (l4 << 2);
#pragma unroll
            for (int n = 0; n < 4; ++n)
#pragma unroll
                for (int j = 0; j < 4; ++j) {
                    float v = acc[m][n][j] + bb[n];
                    ((bf16_t*)o0)[(size_t)(row0 + j) * 4096 + colb + n * 16 + l15] =
                        (bf16_t)(v > 0.f ? v : 0.f);
                }
        }
        return;
    }
    // KERN 0: QKV
    if (bn < 8) {
        const bool isq = bn < 4;
        const float* bias = isq ? bias0 : bias1;
        const int head = (bn & 3) * 4 + wn;
        const int b = (bm * 256) >> 11;
        const int srow0 = (bm * 256 + wm * 128) & 2047;
        bf16_t* dst = (bf16_t*)(isq ? o0 : o1) + ((size_t)(b * 16 + head) << 17);
        float bb[4];
#pragma unroll
        for (int n = 0; n < 4; ++n) bb[n] = bias[head * 64 + n * 16 + l15];
#pragma unroll
        for (int m = 0; m < 8; ++m)
#pragma unroll
            for (int n = 0; n < 4; ++n)
#pragma unroll
                for (int j = 0; j < 4; ++j) {
                    int srw = srow0 + m * 16 + (l4 << 2) + j;
                    float v = acc[m][n][j] + bb[n];
                    if (isq) v *= QSCALE;
                    dst[((size_t)srw << 6) + n * 16 + l15] = (bf16_t)v;
                }
    } else {
        // v: per-wave LDS transpose -> [B,H,64,S] coalesced
        const int head = (bn - 8) * 4 + wn;
        const int b = (bm * 256) >> 11;
        const int sbase = (bm * 256 + wm * 128) & 2047;
        bf16_t* P = L + w * 8192;
        float bb[4];
#pragma unroll
        for (int n = 0; n < 4; ++n) bb[n] = bias2[head * 64 + n * 16 + l15];
#pragma unroll
        for (int m = 0; m < 8; ++m)
#pragma unroll
            for (int n = 0; n < 4; ++n) {
                int d = n * 16 + l15;
                int sl = m * 16 + (l4 << 2);
                bf16x4 pk = {(__bf16)(acc[m][n][0] + bb[n]), (__bf16)(acc[m][n][1] + bb[n]),
                             (__bf16)(acc[m][n][2] + bb[n]), (__bf16)(acc[m][n][3] + bb[n])};
                *(bf16x4*)(P + d * 128 + (sl ^ ((d & 7) << 3))) = pk;
            }
#pragma unroll
        for (int p = 0; p < 16; ++p) {
            int id = p * 64 + lane;
            int d = id >> 4, c8 = (id & 15) * 8;
            bf16x8 vv = *(const bf16x8*)(P + d * 128 + (c8 ^ ((d & 7) << 3)));
            *(bf16x8*)((bf16_t*)o2 + (((size_t)(b * 16 + head) * 64 + d) << 11) + sbase + c8) =
                vv;
        }
    }
}

// ------------- Pipelined 128x128 GEMM, wave=64x64 (C = A @ W^T) -------------
// 4-slot ring, lookahead 3, counted vmcnt. SPLIT=0: +bias +resid -> fp32.
// SPLIT=1: K-split via blockIdx.z, raw partial -> bf16.
template <int SPLIT>
__global__ __launch_bounds__(256, 2) void gemm128sq(
    const bf16_t* __restrict__ A, const bf16_t* __restrict__ Bw, int stride, int Ks,
    const float* __restrict__ bias, const float* __restrict__ resid,
    void* __restrict__ o0, void* __restrict__ o1) {
    __shared__ bf16_t L[4 * 8192];  // 4 slots x (A 128x32 + B 128x32) = 64KB
    const int t = threadIdx.x, lane = t & 63, w = t >> 6;
    const int wr = w >> 1, wc = w & 1;
    const int l15 = lane & 15, l4 = lane >> 4;
    const int bm = blockIdx.x, bn = blockIdx.y;
    const int NT = Ks >> 5;
    const size_t kofs = SPLIT ? (size_t)blockIdx.z * Ks : 0;
    const bf16_t* Ab = A + (size_t)bm * 128 * stride + kofs;
    const bf16_t* Bb = Bw + (size_t)bn * 128 * stride + kofs;
    const int srow = t >> 2, pcol = (t & 3) * 8;
    f32x4 acc[4][4] = {};

    auto STAGE = [&](int tt) {
        bf16_t* s = L + (tt & 3) * 8192;
        const int kb = tt * 32;
#pragma unroll
        for (int i = 0; i < 2; ++i) {
            int row = i * 64 + srow;
            int lcol = pcol ^ bswz(row);
            gload_lds16(Ab + (size_t)row * stride + kb + lcol, s + i * 2048 + t * 8);
            gload_lds16(Bb + (size_t)row * stride + kb + lcol, s + 4096 + i * 2048 + t * 8);
        }
    };

    STAGE(0); STAGE(1); STAGE(2);
    asm volatile("s_waitcnt vmcnt(8)" ::: "memory");
    __builtin_amdgcn_s_barrier();

    for (int tt = 0; tt < NT; ++tt) {
        bf16_t* s = L + (tt & 3) * 8192;
        bf16x8 af[4], bfr[4];
#pragma unroll
        for (int m = 0; m < 4; ++m) {
            int row = wr * 64 + m * 16 + l15;
            af[m] = *(const bf16x8*)(s + row * 32 + ((l4 * 8) ^ bswz(row)));
        }
#pragma unroll
        for (int n = 0; n < 4; ++n) {
            int row = wc * 64 + n * 16 + l15;
            bfr[n] = *(const bf16x8*)(s + 4096 + row * 32 + ((l4 * 8) ^ bswz(row)));
        }
        if (tt + 3 < NT) STAGE(tt + 3);
        __builtin_amdgcn_s_barrier();
        __builtin_amdgcn_s_setprio(1);
#pragma unroll
        for (int m = 0; m < 4; ++m)
#pragma unroll
            for (int n = 0; n < 4; ++n)
                acc[m][n] = __builtin_amdgcn_mfma_f32_16x16x32_bf16(af[m], bfr[n], acc[m][n],
                                                                   0, 0, 0);
        __builtin_amdgcn_s_setprio(0);
        if (tt + 3 < NT)
            asm volatile("s_waitcnt vmcnt(8)" ::: "memory");
        else if (tt + 2 < NT)
            asm volatile("s_waitcnt vmcnt(4)" ::: "memory");
        else
            asm volatile("s_waitcnt vmcnt(0)" ::: "memory");
        __builtin_amdgcn_s_barrier();
    }

#pragma unroll
    for (int m = 0; m < 4; ++m) {
        const int row0 = bm * 128 + wr * 64 + m * 16 + (l4 << 2);
#pragma unroll
        for (int n = 0; n < 4; ++n) {
            const int col = bn * 128 + wc * 64 + n * 16 + l15;
#pragma unroll
            for (int j = 0; j < 4; ++j) {
                const int row = row0 + j;
                if (SPLIT == 0) {
                    ((float*)o0)[(size_t)row * 1024 + col] =
                        resid[(size_t)row * 1024 + col] + acc[m][n][j] + bias[col];
                } else {
                    bf16_t* po = (bf16_t*)(blockIdx.z ? o1 : o0);
                    po[(size_t)row * 1024 + col] = (bf16_t)acc[m][n][j];
                }
            }
        }
    }
}

// ---- FFN2 combine: out = p0 + p1 + resid + bias (fp32), 4096x1024 ----------
__global__ __launch_bounds__(256) void ffn2_combine(
    const bf16_t* __restrict__ p0, const bf16_t* __restrict__ p1,
    const float* __restrict__ resid, const float* __restrict__ bias,
    float* __restrict__ out) {
    int i = blockIdx.x * 256 + threadIdx.x;  // float4 index, 1M total
    float4 r = ((const float4*)resid)[i];
    bf16x4 a = ((const bf16x4*)p0)[i];
    bf16x4 b = ((const bf16x4*)p1)[i];
    float4 bs = ((const float4*)bias)[i & 255];
    float4 o;
    o.x = r.x + (float)a.x + (float)b.x + bs.x;
    o.y = r.y + (float)a.y + (float)b.y + bs.y;
    o.z = r.z + (float)a.z + (float)b.z + bs.z;
    o.w = r.w + (float)a.w + (float)b.w + bs.w;
    ((float4*)out)[i] = o;
}

// --------------------------- Flash attention (R8 verbatim) ------------------
// 1-D grid 512, XCD-swizzled: all 16 q-tiles of a head on one XCD (T1).
// 4 waves x 32 q-rows. KV tile = 64 keys. 32x32x16 MFMA, swapped QK^T and PV.
__global__ __launch_bounds__(256, 2) void attn_kernel(const bf16_t* __restrict__ q,
                                                      const bf16_t* __restrict__ k,
                                                      const bf16_t* __restrict__ vt,
                                                      bf16_t* __restrict__ ctx) {
    __shared__ bf16_t Kl[64 * 64];
    __shared__ bf16_t Vl[64 * 64];
    const int t = threadIdx.x, lane = t & 63, w = t >> 6;
    const int bid = blockIdx.x;
    const int xcd = bid & 7, j = bid >> 3;
    const int bh = xcd + ((j >> 4) << 3);
    const int qx = j & 15;
    const bf16_t* qg = q + (size_t)bh * 2048 * 64;
    const bf16_t* kg = k + (size_t)bh * 2048 * 64;
    const bf16_t* vg = vt + (size_t)bh * 64 * 2048;
    const int r = t >> 3, c8 = (t & 7) * 8;
    const int l31 = lane & 31, h = lane >> 5;
    const int qrow = qx * 128 + w * 32 + l31;

    bf16x8 qf[4];
#pragma unroll
    for (int kd = 0; kd < 4; ++kd)
        qf[kd] = *(const bf16x8*)(qg + (size_t)qrow * 64 + kd * 16 + h * 8);

    f32x16 o0 = {}, o1 = {};
    float mi = -1e30f, li = 0.f;

    {
        bf16x8 k0 = *(const bf16x8*)(kg + (size_t)r * 64 + c8);
        bf16x8 k1 = *(const bf16x8*)(kg + (size_t)(r + 32) * 64 + c8);
        bf16x8 v0 = *(const bf16x8*)(vg + (size_t)r * 2048 + c8);
        bf16x8 v1 = *(const bf16x8*)(vg + (size_t)(r + 32) * 2048 + c8);
        *(bf16x8*)(Kl + swz(r, c8)) = k0;
        *(bf16x8*)(Kl + swz(r + 32, c8)) = k1;
        *(bf16x8*)(Vl + swz(r, c8)) = v0;
        *(bf16x8*)(Vl + swz(r + 32, c8)) = v1;
    }

    for (int kt = 0; kt < 2048; kt += 64) {
        __syncthreads();
        bf16x8 k0, k1, v0, v1;
        const bool more = (kt + 64) < 2048;
        if (more) {
            k0 = *(const bf16x8*)(kg + (size_t)(kt + 64 + r) * 64 + c8);
            k1 = *(const bf16x8*)(kg + (size_t)(kt + 64 + r + 32) * 64 + c8);
            v0 = *(const bf16x8*)(vg + (size_t)r * 2048 + kt + 64 + c8);
            v1 = *(const bf16x8*)(vg + (size_t)(r + 32) * 2048 + kt + 64 + c8);
        }
        f32x16 sT0 = {}, sT1 = {};
        __builtin_amdgcn_s_setprio(1);
#pragma unroll
        for (int kd = 0; kd < 4; ++kd) {
            bf16x8 ka0 = *(const bf16x8*)(Kl + swz(l31, kd * 16 + h * 8));
            bf16x8 ka1 = *(const bf16x8*)(Kl + swz(32 + l31, kd * 16 + h * 8));
            sT0 = __builtin_amdgcn_mfma_f32_32x32x16_bf16(ka0, qf[kd], sT0, 0, 0, 0);
            sT1 = __builtin_amdgcn_mfma_f32_32x32x16_bf16(ka1, qf[kd], sT1, 0, 0, 0);
        }
        __builtin_amdgcn_s_setprio(0);
        float mx = fmaxf(sT0[0], sT0[1]);
#pragma unroll
        for (int i = 2; i < 16; ++i) mx = fmaxf(mx, sT0[i]);
#pragma unroll
        for (int i = 0; i < 16; ++i) mx = fmaxf(mx, sT1[i]);
        mx = fmaxf(mx, __shfl_xor(mx, 32));
        if (!__all(mx <= mi + 8.f)) {
            float mn = fmaxf(mi, mx);
            float al = __builtin_amdgcn_exp2f(mi - mn);
            mi = mn;
            li *= al;
            o0 *= al;
            o1 *= al;
        }
        f32x16 e0, e1;
        float rs = 0.f;
#pragma unroll
        for (int i = 0; i < 16; ++i) {
            e0[i] = __builtin_amdgcn_exp2f(sT0[i] - mi);
            rs += e0[i];
        }
#pragma unroll
        for (int i = 0; i < 16; ++i) {
            e1[i] = __builtin_amdgcn_exp2f(sT1[i] - mi);
            rs += e1[i];
        }
        rs += __shfl_xor(rs, 32);
        li += rs;
        bf16x8 pa[4];
#pragma unroll
        for (int kd = 0; kd < 4; ++kd) {
            const f32x16& e = (kd < 2) ? e0 : e1;
            const int R0l = 8 * (kd & 1);
            const int R0h = R0l + 4;
            unsigned U0 = cvtpk(e[R0l + 0], e[R0l + 1]);
            unsigned V0 = cvtpk(e[R0l + 2], e[R0l + 3]);
            unsigned U1 = cvtpk(e[R0h + 0], e[R0h + 1]);
            unsigned V1 = cvtpk(e[R0h + 2], e[R0h + 3]);
            uint32x2 ru = __builtin_amdgcn_permlane32_swap(U0, U1, false, false);
            uint32x2 rv = __builtin_amdgcn_permlane32_swap(V0, V1, false, false);
            uint32x4 pw = {ru.x, rv.x, ru.y, rv.y};
            pa[kd] = __builtin_bit_cast(bf16x8, pw);
        }
        __builtin_amdgcn_s_setprio(1);
#pragma unroll
        for (int kd = 0; kd < 4; ++kd) {
            bf16x8 va0 = *(const bf16x8*)(Vl + swz(l31, kd * 16 + h * 8));
            bf16x8 va1 = *(const bf16x8*)(Vl + swz(32 + l31, kd * 16 + h * 8));
            o0 = __builtin_amdgcn_mfma_f32_32x32x16_bf16(va0, pa[kd], o0, 0, 0, 0);
            o1 = __builtin_amdgcn_mfma_f32_32x32x16_bf16(va1, pa[kd], o1, 0, 0, 0);
        }
        __builtin_amdgcn_s_setprio(0);
        __syncthreads();
        if (more) {
            *(bf16x8*)(Kl + swz(r, c8)) = k0;
            *(bf16x8*)(Kl + swz(r + 32, c8)) = k1;
            *(bf16x8*)(Vl + swz(r, c8)) = v0;
            *(bf16x8*)(Vl + swz(r + 32, c8)) = v1;
        }
    }
    float inv = 1.f / li;
    size_t base = ((size_t)(bh >> 4) * 2048 + qrow) * 1024 + (bh & 15) * 64;
#pragma unroll
    for (int g = 0; g < 4; ++g) {
        bf16x4 ov0 = {(__bf16)(o0[4 * g + 0] * inv), (__bf16)(o0[4 * g + 1] * inv),
                      (__bf16)(o0[4 * g + 2] * inv), (__bf16)(o0[4 * g + 3] * inv)};
        *(bf16x4*)(ctx + base + 8 * g + 4 * h) = ov0;
        bf16x4 ov1 = {(__bf16)(o1[4 * g + 0] * inv), (__bf16)(o1[4 * g + 1] * inv),
                      (__bf16)(o1[4 * g + 2] * inv), (__bf16)(o1[4 * g + 3] * inv)};
        *(bf16x4*)(ctx + base + 32 + 8 * g + 4 * h) = ov1;
    }
}

// ---------------------------------------------------------------------------
extern "C" void kernel_launch(void* const* d_in, const int* in_sizes, int n_in,
                              void* d_out, int out_size, void* d_ws, size_t ws_size,
                              hipStream_t stream) {
    const float* x = (const float*)d_in[0];
    const float* wq = (const float*)d_in[2];
    const float* bq = (const float*)d_in[3];
    const float* wk = (const float*)d_in[4];
    const float* bk = (const float*)d_in[5];
    const float* wv = (const float*)d_in[6];
    const float* bv = (const float*)d_in[7];
    const float* wo = (const float*)d_in[8];
    const float* bo = (const float*)d_in[9];
    const float* w1 = (const float*)d_in[10];
    const float* b1 = (const float*)d_in[11];
    const float* w2 = (const float*)d_in[12];
    const float* b2 = (const float*)d_in[13];
    const float* gamma1 = (const float*)d_in[14];
    const float* beta1 = (const float*)d_in[15];
    const float* gamma2 = (const float*)d_in[16];
    const float* beta2 = (const float*)d_in[17];

    char* ws = (char*)d_ws;
    bf16_t* wqkv = (bf16_t*)(ws + 0);
    bf16_t* wob = (bf16_t*)(ws + 6 * MB);
    bf16_t* w1b = (bf16_t*)(ws + 8 * MB);
    bf16_t* w2b = (bf16_t*)(ws + 16 * MB);
    bf16_t* xnb = (bf16_t*)(ws + 24 * MB);
    bf16_t* qb = (bf16_t*)(ws + 32 * MB);
    bf16_t* kb = (bf16_t*)(ws + 40 * MB);
    bf16_t* vtb = (bf16_t*)(ws + 48 * MB);
    bf16_t* ctxb = (bf16_t*)(ws + 56 * MB);
    float* x1 = (float*)(ws + 64 * MB);
    bf16_t* hb = (bf16_t*)(ws + 32 * MB);  // reuses q/k/vT/ctx (dead by FFN1)
    bf16_t* p0 = (bf16_t*)(ws + 0);        // FFN2 partial z=0 (wqkv/wob dead)
    bf16_t* p1 = (bf16_t*)(ws + 24 * MB);  // FFN2 partial z=1 (xnb dead)

    // weight converts + LN1 (merged)
    cvt_ln<<<13312, 256, 0, stream>>>(wq, wk, wv, wo, w1, w2, wqkv, wob, w1b, w2b, x, xnb,
                                      gamma1, beta1);
    // QKV fused GEMM (256x256, N=3072)
    gemm256<0><<<dim3(16, 12), 512, 0, stream>>>(xnb, wqkv, 1024, bq, bk, bv, qb, kb, vtb);
    // attention (single kernel, XCD-swizzled, R8 core)
    attn_kernel<<<512, 256, 0, stream>>>(qb, kb, vtb, ctxb);
    // out-proj + residual -> x1 (fp32)
    gemm128sq<0><<<dim3(32, 8), 256, 0, stream>>>(ctxb, wob, 1024, 1024, bo, x, x1, nullptr);
    // LN2
    ln_kernel<<<1024, 256, 0, stream>>>(x1, xnb, gamma2, beta2);
    // FFN1 + relu (256x256, N=4096)
    gemm256<1><<<dim3(16, 16), 512, 0, stream>>>(xnb, w1b, 1024, b1, nullptr, nullptr, hb,
                                                 nullptr, nullptr);
    // FFN2 K-split-2 -> bf16 partials, then combine with residual -> d_out
    gemm128sq<1><<<dim3(32, 8, 2), 256, 0, stream>>>(hb, w2b, 4096, 2048, nullptr, nullptr,
                                                     p0, p1);
    ffn2_combine<<<4096, 256, 0, stream>>>(p0, p1, x1, b2, (float*)d_out);
}